// Round 2
// baseline (1642.138 us; speedup 1.0000x reference)
//
#include <hip/hip_runtime.h>
#include <hip/hip_bf16.h>

#define NEG_SLOPE 0.2f

// ---------------------------------------------------------------- self loops
__global__ void loop_accum_k(const float* __restrict__ ea, const int* __restrict__ dst,
                             float* __restrict__ sums, float* __restrict__ cnt, int E) {
  int idx = blockIdx.x * blockDim.x + threadIdx.x;
  if (idx >= E * 16) return;
  int e = idx >> 4, c = idx & 15;
  int d = dst[e];
  atomicAdd(&sums[(size_t)d * 16 + c], ea[idx]);
  if (c == 0) atomicAdd(&cnt[d], 1.0f);
}

__global__ void loop_fin_k(float* __restrict__ sums, const float* __restrict__ cnt, int N) {
  int idx = blockIdx.x * blockDim.x + threadIdx.x;
  if (idx >= N * 16) return;
  sums[idx] = sums[idx] / fmaxf(cnt[idx >> 4], 1.0f);
}

// ------------------------------------------------- layer1 node transform (128->64 x2)
__global__ __launch_bounds__(128) void transform1_k(
    const float* __restrict__ x, const float* __restrict__ wl, const float* __restrict__ wr,
    float* __restrict__ xl, float* __restrict__ xr, int N) {
  __shared__ float wS[128 * 128];  // [k][j]: j<64 -> wl, j>=64 -> wr   (64 KB)
  __shared__ float xs[4][128];
  int t = threadIdx.x;
  for (int i = t; i < 128 * 64; i += 128) {
    int k = i >> 6, j = i & 63;
    wS[k * 128 + j]      = wl[i];
    wS[k * 128 + 64 + j] = wr[i];
  }
  __syncthreads();
  for (int base = blockIdx.x * 4; base < N; base += gridDim.x * 4) {
    for (int i = t; i < 512; i += 128) {
      int node = base + (i >> 7);
      xs[i >> 7][i & 127] = (node < N) ? x[(size_t)node * 128 + (i & 127)] : 0.f;
    }
    __syncthreads();
    float a0 = 0.f, a1 = 0.f, a2 = 0.f, a3 = 0.f;
#pragma unroll
    for (int k = 0; k < 128; ++k) {
      float w = wS[k * 128 + t];
      a0 += xs[0][k] * w; a1 += xs[1][k] * w; a2 += xs[2][k] * w; a3 += xs[3][k] * w;
    }
    float* dp = (t < 64) ? xl : xr;
    int j = t & 63;
    if (base + 0 < N) dp[(size_t)(base + 0) * 64 + j] = a0;
    if (base + 1 < N) dp[(size_t)(base + 1) * 64 + j] = a1;
    if (base + 2 < N) dp[(size_t)(base + 2) * 64 + j] = a2;
    if (base + 3 < N) dp[(size_t)(base + 3) * 64 + j] = a3;
    __syncthreads();
  }
}

// ------------------------------------------------- layer2 node transform (64->32 x2)
__global__ __launch_bounds__(64) void transform2_k(
    const float* __restrict__ h, const float* __restrict__ wl, const float* __restrict__ wr,
    float* __restrict__ xl, float* __restrict__ xr, int N) {
  __shared__ float wS[64 * 64];  // [k][j]: j<32 -> wl, j>=32 -> wr
  __shared__ float xs[8][64];
  int t = threadIdx.x;
  for (int i = t; i < 64 * 32; i += 64) {
    int k = i >> 5, j = i & 31;
    wS[k * 64 + j]      = wl[i];
    wS[k * 64 + 32 + j] = wr[i];
  }
  __syncthreads();
  for (int base = blockIdx.x * 8; base < N; base += gridDim.x * 8) {
    for (int i = t; i < 512; i += 64) {
      int node = base + (i >> 6);
      xs[i >> 6][i & 63] = (node < N) ? h[(size_t)node * 64 + (i & 63)] : 0.f;
    }
    __syncthreads();
    float acc[8] = {0.f, 0.f, 0.f, 0.f, 0.f, 0.f, 0.f, 0.f};
#pragma unroll
    for (int k = 0; k < 64; ++k) {
      float w = wS[k * 64 + t];
#pragma unroll
      for (int i = 0; i < 8; ++i) acc[i] += xs[i][k] * w;
    }
    float* dp = (t < 32) ? xl : xr;
    int j = t & 31;
#pragma unroll
    for (int i = 0; i < 8; ++i)
      if (base + i < N) dp[(size_t)(base + i) * 32 + j] = acc[i];
    __syncthreads();
  }
}

// ------------------------------------------------- edge pass layer1: 1 wave / edge
// lane = h*32+c.  Accumulates UNNORMALIZED softmax numerator + denominator.
__global__ __launch_bounds__(256) void edge_pass1_k(
    const int* __restrict__ srcA, const int* __restrict__ dstA,
    const float* __restrict__ ea, const float* __restrict__ loopA,
    const float* __restrict__ we, const float* __restrict__ att,
    const float* __restrict__ xl, const float* __restrict__ xr,
    float* __restrict__ acc, float* __restrict__ s, int E, int Etot) {
  int wid = (blockIdx.x * blockDim.x + threadIdx.x) >> 6;
  int lane = threadIdx.x & 63;
  if (wid >= Etot) return;
  int sN, dN; const float* eap;
  if (wid < E) { sN = srcA[wid]; dN = dstA[wid]; eap = ea + (size_t)wid * 16; }
  else         { sN = dN = wid - E;              eap = loopA + (size_t)(wid - E) * 16; }
  float ef = 0.f;
#pragma unroll
  for (int k = 0; k < 16; ++k) ef += eap[k] * we[k * 64 + lane];
  float xlv = xl[(size_t)sN * 64 + lane];
  float m = xlv + xr[(size_t)dN * 64 + lane] + ef;
  m = (m > 0.f) ? m : NEG_SLOPE * m;
  float sc = m * att[lane];
#pragma unroll
  for (int off = 1; off < 32; off <<= 1) sc += __shfl_xor(sc, off);  // sum within 32-lane half
  float ex = __expf(sc);
  atomicAdd(&acc[(size_t)dN * 64 + lane], ex * xlv);
  if ((lane & 31) == 0) atomicAdd(&s[(size_t)dN * 2 + (lane >> 5)], ex);
}

// ------------------------------------------------- edge pass layer2: 2 edges / wave
__global__ __launch_bounds__(256) void edge_pass2_k(
    const int* __restrict__ srcA, const int* __restrict__ dstA,
    const float* __restrict__ ea, const float* __restrict__ loopA,
    const float* __restrict__ we, const float* __restrict__ att,
    const float* __restrict__ xl, const float* __restrict__ xr,
    float* __restrict__ acc, float* __restrict__ s, int E, int Etot) {
  int gtid = blockIdx.x * blockDim.x + threadIdx.x;
  int e = (gtid >> 5);           // one 32-lane half per edge
  int c = threadIdx.x & 31;
  if (e >= Etot) return;
  int sN, dN; const float* eap;
  if (e < E) { sN = srcA[e]; dN = dstA[e]; eap = ea + (size_t)e * 16; }
  else       { sN = dN = e - E;            eap = loopA + (size_t)(e - E) * 16; }
  float ef = 0.f;
#pragma unroll
  for (int k = 0; k < 16; ++k) ef += eap[k] * we[k * 32 + c];
  float xlv = xl[(size_t)sN * 32 + c];
  float m = xlv + xr[(size_t)dN * 32 + c] + ef;
  m = (m > 0.f) ? m : NEG_SLOPE * m;
  float sc = m * att[c];
#pragma unroll
  for (int off = 1; off < 32; off <<= 1) sc += __shfl_xor(sc, off);
  float ex = __expf(sc);
  atomicAdd(&acc[(size_t)dN * 32 + c], ex * xlv);
  if (c == 0) atomicAdd(&s[dN], ex);
}

// ------------------------------------------------- finalize: /denom + bias + relu
__global__ void finalize1_k(float* __restrict__ acc, const float* __restrict__ s,
                            const float* __restrict__ b, int N) {
  int idx = blockIdx.x * blockDim.x + threadIdx.x;
  if (idx >= N * 64) return;
  int n = idx >> 6, j = idx & 63;
  float v = acc[idx] / fmaxf(s[(size_t)n * 2 + (j >> 5)], 1e-16f) + b[j];
  acc[idx] = fmaxf(v, 0.f);
}

__global__ void finalize2_k(float* __restrict__ acc, const float* __restrict__ s,
                            const float* __restrict__ b, int N) {
  int idx = blockIdx.x * blockDim.x + threadIdx.x;
  if (idx >= N * 32) return;
  int n = idx >> 5, j = idx & 31;
  float v = acc[idx] / fmaxf(s[n], 1e-16f) + b[j];
  acc[idx] = fmaxf(v, 0.f);
}

// ------------------------------------------------- mean pool + fc
__global__ void pool_k(const float* __restrict__ h, const int* __restrict__ batch,
                       float* __restrict__ pooled, float* __restrict__ pcnt, int N) {
  int idx = blockIdx.x * blockDim.x + threadIdx.x;
  if (idx >= N * 32) return;
  int n = idx >> 5, c = idx & 31;
  int g = batch[n];
  atomicAdd(&pooled[(size_t)g * 32 + c], h[idx]);
  if (c == 0) atomicAdd(&pcnt[g], 1.0f);
}

__global__ void fc_k(const float* __restrict__ pooled, const float* __restrict__ pcnt,
                     const float* __restrict__ wfc, const float* __restrict__ bfc,
                     float* __restrict__ out, int G) {
  int idx = blockIdx.x * blockDim.x + threadIdx.x;
  if (idx >= G * 32) return;
  int g = idx >> 5, o = idx & 31;
  float a = 0.f;
#pragma unroll
  for (int c = 0; c < 32; ++c) a += pooled[(size_t)g * 32 + c] * wfc[c * 32 + o];
  out[idx] = a / fmaxf(pcnt[g], 1.0f) + bfc[o];
}

// ----------------------------------------------------------------- launcher
extern "C" void kernel_launch(void* const* d_in, const int* in_sizes, int n_in,
                              void* d_out, int out_size, void* d_ws, size_t ws_size,
                              hipStream_t stream) {
  const float* x   = (const float*)d_in[0];
  const int*   ei  = (const int*)d_in[1];
  const float* ea  = (const float*)d_in[2];
  const int*   bat = (const int*)d_in[3];
  const float* wl1 = (const float*)d_in[4];
  const float* wr1 = (const float*)d_in[5];
  const float* we1 = (const float*)d_in[6];
  const float* at1 = (const float*)d_in[7];
  const float* b1  = (const float*)d_in[8];
  const float* wl2 = (const float*)d_in[9];
  const float* wr2 = (const float*)d_in[10];
  const float* we2 = (const float*)d_in[11];
  const float* at2 = (const float*)d_in[12];
  const float* b2  = (const float*)d_in[13];
  const float* wfc = (const float*)d_in[14];
  const float* bfc = (const float*)d_in[15];

  const int N = in_sizes[0] / 128;
  const int E = in_sizes[1] / 2;
  const int Etot = E + N;
  const int G = 256;
  const int* srcA = ei;
  const int* dstA = ei + E;

  // workspace layout (f32), with layer2 aliasing dead layer1 buffers
  float* loopA = (float*)d_ws;                 // N*16
  float* cnt   = loopA + (size_t)N * 16;       // N
  float* xl1   = cnt + N;                      // N*64  (region C)
  float* xr1   = xl1 + (size_t)N * 64;         // N*64  (region D)
  float* acc1  = xr1 + (size_t)N * 64;         // N*64  -> becomes h1
  float* s1    = acc1 + (size_t)N * 64;        // N*2
  // aliases (valid after layer-1 edge pass is done):
  float* xl2    = xl1;                         // N*32
  float* acc2   = xl1 + (size_t)N * 32;        // N*32
  float* xr2    = xr1;                         // N*32
  float* s2     = xr1 + (size_t)N * 32;        // N
  float* pooled = s2 + N;                      // G*32
  float* pcnt   = pooled + (size_t)G * 32;     // G

  // ---- stage A: self-loop attrs
  hipMemsetAsync(loopA, 0, (size_t)N * 16 * sizeof(float), stream);
  hipMemsetAsync(cnt,   0, (size_t)N * sizeof(float), stream);
  hipMemsetAsync(acc1,  0, (size_t)N * 64 * sizeof(float), stream);
  hipMemsetAsync(s1,    0, (size_t)N * 2 * sizeof(float), stream);
  {
    int tot = E * 16;
    loop_accum_k<<<(tot + 255) / 256, 256, 0, stream>>>(ea, dstA, loopA, cnt, E);
    tot = N * 16;
    loop_fin_k<<<(tot + 255) / 256, 256, 0, stream>>>(loopA, cnt, N);
  }

  // ---- layer 1
  transform1_k<<<2048, 128, 0, stream>>>(x, wl1, wr1, xl1, xr1, N);
  {
    long long thr = (long long)Etot * 64;
    int blocks = (int)((thr + 255) / 256);
    edge_pass1_k<<<blocks, 256, 0, stream>>>(srcA, dstA, ea, loopA, we1, at1,
                                             xl1, xr1, acc1, s1, E, Etot);
  }
  finalize1_k<<<(N * 64 + 255) / 256, 256, 0, stream>>>(acc1, s1, b1, N);

  // ---- layer 2
  transform2_k<<<2048, 64, 0, stream>>>(acc1, wl2, wr2, xl2, xr2, N);
  hipMemsetAsync(acc2,   0, (size_t)N * 32 * sizeof(float), stream);
  hipMemsetAsync(s2,     0, (size_t)N * sizeof(float), stream);
  hipMemsetAsync(pooled, 0, (size_t)G * 32 * sizeof(float), stream);
  hipMemsetAsync(pcnt,   0, (size_t)G * sizeof(float), stream);
  {
    long long thr = (long long)Etot * 32;
    int blocks = (int)((thr + 255) / 256);
    edge_pass2_k<<<blocks, 256, 0, stream>>>(srcA, dstA, ea, loopA, we2, at2,
                                             xl2, xr2, acc2, s2, E, Etot);
  }
  finalize2_k<<<(N * 32 + 255) / 256, 256, 0, stream>>>(acc2, s2, b2, N);

  // ---- pool + fc
  pool_k<<<(N * 32 + 255) / 256, 256, 0, stream>>>(acc2, bat, pooled, pcnt, N);
  fc_k<<<(G * 32 + 255) / 256, 256, 0, stream>>>(pooled, pcnt, wfc, bfc,
                                                 (float*)d_out, G);
}

// Round 3
// 1199.272 us; speedup vs baseline: 1.3693x; 1.3693x over previous
//
#include <hip/hip_runtime.h>
#include <hip/hip_bf16.h>

#define NEG_SLOPE 0.2f

// ------------------------------------------------------------ CSR build
__global__ void zero_int_k(int* __restrict__ p, int n) {
  int i = blockIdx.x * blockDim.x + threadIdx.x;
  if (i < n) p[i] = 0;
}

__global__ void deg_count_k(const int* __restrict__ dstA, int* __restrict__ deg, int E) {
  int e = blockIdx.x * blockDim.x + threadIdx.x;
  if (e < E) atomicAdd(&deg[dstA[e]], 1);
}

// exclusive scan, 3 phases (N <= 512*256)
__global__ void scan1_k(const int* __restrict__ deg, int* __restrict__ rowptr,
                        int* __restrict__ aux, int N) {
  __shared__ int sh[256];
  int t = threadIdx.x, i = blockIdx.x * 256 + t;
  int v = (i < N) ? deg[i] : 0;
  sh[t] = v; __syncthreads();
  for (int off = 1; off < 256; off <<= 1) {
    int x = (t >= off) ? sh[t - off] : 0;
    __syncthreads();
    sh[t] += x;
    __syncthreads();
  }
  if (i < N) rowptr[i] = sh[t] - v;          // exclusive within block
  if (t == 255) aux[blockIdx.x] = sh[255];   // block total
}

__global__ void scan2_k(int* __restrict__ aux, int naux) {
  __shared__ int sh[512];
  int t = threadIdx.x;
  int v = (t < naux) ? aux[t] : 0;
  sh[t] = v; __syncthreads();
  for (int off = 1; off < 512; off <<= 1) {
    int x = (t >= off) ? sh[t - off] : 0;
    __syncthreads();
    sh[t] += x;
    __syncthreads();
  }
  if (t < naux) aux[t] = sh[t] - v;          // exclusive block offsets
}

__global__ void scan3_k(int* __restrict__ rowptr, int* __restrict__ cursor,
                        const int* __restrict__ aux, int N, int E) {
  int i = blockIdx.x * blockDim.x + threadIdx.x;
  if (i < N) {
    int r = rowptr[i] + aux[i >> 8];
    rowptr[i] = r;
    cursor[i] = r;
  } else if (i == N) {
    rowptr[N] = E;
  }
}

__global__ void scatter_k(const int* __restrict__ srcA, const int* __restrict__ dstA,
                          int* __restrict__ cursor, int* __restrict__ csr_src,
                          int* __restrict__ csr_eid, int E) {
  int e = blockIdx.x * blockDim.x + threadIdx.x;
  if (e >= E) return;
  int pos = atomicAdd(&cursor[dstA[e]], 1);
  csr_src[pos] = srcA[e];
  csr_eid[pos] = e;
}

// ------------------------------------------------------------ self-loop attr (pull)
__global__ void loop_attr_k(const int* __restrict__ rowptr, const int* __restrict__ csr_eid,
                            const float* __restrict__ ea, float* __restrict__ loopA, int N) {
  int idx = blockIdx.x * blockDim.x + threadIdx.x;
  if (idx >= N * 16) return;
  int n = idx >> 4, c = idx & 15;
  int rs = rowptr[n], re = rowptr[n + 1];
  float sum = 0.f;
  for (int i = rs; i < re; ++i) sum += ea[(size_t)csr_eid[i] * 16 + c];
  loopA[idx] = sum / fmaxf((float)(re - rs), 1.f);
}

// ------------------------------------------------- layer1 node transform (128->64 x2)
__global__ __launch_bounds__(128) void transform1_k(
    const float* __restrict__ x, const float* __restrict__ wl, const float* __restrict__ wr,
    float* __restrict__ xl, float* __restrict__ xr, int N) {
  __shared__ float wS[128 * 128];
  __shared__ float xs[4][128];
  int t = threadIdx.x;
  for (int i = t; i < 128 * 64; i += 128) {
    int k = i >> 6, j = i & 63;
    wS[k * 128 + j]      = wl[i];
    wS[k * 128 + 64 + j] = wr[i];
  }
  __syncthreads();
  for (int base = blockIdx.x * 4; base < N; base += gridDim.x * 4) {
    for (int i = t; i < 512; i += 128) {
      int node = base + (i >> 7);
      xs[i >> 7][i & 127] = (node < N) ? x[(size_t)node * 128 + (i & 127)] : 0.f;
    }
    __syncthreads();
    float a0 = 0.f, a1 = 0.f, a2 = 0.f, a3 = 0.f;
#pragma unroll
    for (int k = 0; k < 128; ++k) {
      float w = wS[k * 128 + t];
      a0 += xs[0][k] * w; a1 += xs[1][k] * w; a2 += xs[2][k] * w; a3 += xs[3][k] * w;
    }
    float* dp = (t < 64) ? xl : xr;
    int j = t & 63;
    if (base + 0 < N) dp[(size_t)(base + 0) * 64 + j] = a0;
    if (base + 1 < N) dp[(size_t)(base + 1) * 64 + j] = a1;
    if (base + 2 < N) dp[(size_t)(base + 2) * 64 + j] = a2;
    if (base + 3 < N) dp[(size_t)(base + 3) * 64 + j] = a3;
    __syncthreads();
  }
}

// ------------------------------------------------- layer2 node transform (64->32 x2)
__global__ __launch_bounds__(64) void transform2_k(
    const float* __restrict__ h, const float* __restrict__ wl, const float* __restrict__ wr,
    float* __restrict__ xl, float* __restrict__ xr, int N) {
  __shared__ float wS[64 * 64];
  __shared__ float xs[8][64];
  int t = threadIdx.x;
  for (int i = t; i < 64 * 32; i += 64) {
    int k = i >> 5, j = i & 31;
    wS[k * 64 + j]      = wl[i];
    wS[k * 64 + 32 + j] = wr[i];
  }
  __syncthreads();
  for (int base = blockIdx.x * 8; base < N; base += gridDim.x * 8) {
    for (int i = t; i < 512; i += 64) {
      int node = base + (i >> 6);
      xs[i >> 6][i & 63] = (node < N) ? h[(size_t)node * 64 + (i & 63)] : 0.f;
    }
    __syncthreads();
    float acc[8] = {0.f, 0.f, 0.f, 0.f, 0.f, 0.f, 0.f, 0.f};
#pragma unroll
    for (int k = 0; k < 64; ++k) {
      float w = wS[k * 64 + t];
#pragma unroll
      for (int i = 0; i < 8; ++i) acc[i] += xs[i][k] * w;
    }
    float* dp = (t < 32) ? xl : xr;
    int j = t & 31;
#pragma unroll
    for (int i = 0; i < 8; ++i)
      if (base + i < N) dp[(size_t)(base + i) * 32 + j] = acc[i];
    __syncthreads();
  }
}

// ------------------------------------------------- GAT layer1: one wave per node (pull)
__global__ __launch_bounds__(256) void gat1_k(
    const int* __restrict__ rowptr, const int* __restrict__ csr_src,
    const int* __restrict__ csr_eid, const float* __restrict__ ea,
    const float* __restrict__ loopA, const float* __restrict__ we,
    const float* __restrict__ att, const float* __restrict__ b,
    const float* __restrict__ xl, const float* __restrict__ xr,
    float* __restrict__ h, int N) {
  __shared__ float weS[16 * 64];
  __shared__ float attS[64];
  __shared__ float bS[64];
  int t = threadIdx.x;
  for (int i = t; i < 16 * 64; i += 256) weS[i] = we[i];
  if (t < 64) { attS[t] = att[t]; bS[t] = b[t]; }
  __syncthreads();
  int lane = t & 63;
  int wid = (blockIdx.x * blockDim.x + t) >> 6;
  int nwaves = (gridDim.x * blockDim.x) >> 6;
  for (int n = wid; n < N; n += nwaves) {
    float xr_v = xr[(size_t)n * 64 + lane];
    float xl_s = xl[(size_t)n * 64 + lane];
    // self loop
    const float4* lp4 = (const float4*)(loopA + (size_t)n * 16);
    float4 l0 = lp4[0], l1 = lp4[1], l2 = lp4[2], l3 = lp4[3];
    float ef = l0.x * weS[0 * 64 + lane] + l0.y * weS[1 * 64 + lane] +
               l0.z * weS[2 * 64 + lane] + l0.w * weS[3 * 64 + lane] +
               l1.x * weS[4 * 64 + lane] + l1.y * weS[5 * 64 + lane] +
               l1.z * weS[6 * 64 + lane] + l1.w * weS[7 * 64 + lane] +
               l2.x * weS[8 * 64 + lane] + l2.y * weS[9 * 64 + lane] +
               l2.z * weS[10 * 64 + lane] + l2.w * weS[11 * 64 + lane] +
               l3.x * weS[12 * 64 + lane] + l3.y * weS[13 * 64 + lane] +
               l3.z * weS[14 * 64 + lane] + l3.w * weS[15 * 64 + lane];
    float m = xl_s + xr_v + ef;
    m = (m > 0.f) ? m : NEG_SLOPE * m;
    float sc = m * attS[lane];
#pragma unroll
    for (int off = 1; off < 32; off <<= 1) sc += __shfl_xor(sc, off);
    float ex = __expf(sc);
    float num = ex * xl_s;
    float den = ex;
    int rs = rowptr[n], re = rowptr[n + 1];
    for (int base = rs; base < re; base += 64) {
      int cnt = min(64, re - base);
      int s_l = 0, e_l = 0;
      if (lane < cnt) { s_l = csr_src[base + lane]; e_l = csr_eid[base + lane]; }
      for (int i = 0; i < cnt; ++i) {
        int s = __shfl(s_l, i);
        int eid = __shfl(e_l, i);
        float xlv = xl[(size_t)s * 64 + lane];
        const float4* e4 = (const float4*)(ea + (size_t)eid * 16);
        float4 a0 = e4[0], a1 = e4[1], a2 = e4[2], a3 = e4[3];
        float ef2 = a0.x * weS[0 * 64 + lane] + a0.y * weS[1 * 64 + lane] +
                    a0.z * weS[2 * 64 + lane] + a0.w * weS[3 * 64 + lane] +
                    a1.x * weS[4 * 64 + lane] + a1.y * weS[5 * 64 + lane] +
                    a1.z * weS[6 * 64 + lane] + a1.w * weS[7 * 64 + lane] +
                    a2.x * weS[8 * 64 + lane] + a2.y * weS[9 * 64 + lane] +
                    a2.z * weS[10 * 64 + lane] + a2.w * weS[11 * 64 + lane] +
                    a3.x * weS[12 * 64 + lane] + a3.y * weS[13 * 64 + lane] +
                    a3.z * weS[14 * 64 + lane] + a3.w * weS[15 * 64 + lane];
        float mm = xlv + xr_v + ef2;
        mm = (mm > 0.f) ? mm : NEG_SLOPE * mm;
        float s2 = mm * attS[lane];
#pragma unroll
        for (int off = 1; off < 32; off <<= 1) s2 += __shfl_xor(s2, off);
        float e2 = __expf(s2);
        num += e2 * xlv;
        den += e2;
      }
    }
    h[(size_t)n * 64 + lane] = fmaxf(num / fmaxf(den, 1e-16f) + bS[lane], 0.f);
  }
}

// ------------------------------------------------- GAT layer2: half-wave per node
__global__ __launch_bounds__(256) void gat2_k(
    const int* __restrict__ rowptr, const int* __restrict__ csr_src,
    const int* __restrict__ csr_eid, const float* __restrict__ ea,
    const float* __restrict__ loopA, const float* __restrict__ we,
    const float* __restrict__ att, const float* __restrict__ b,
    const float* __restrict__ xl, const float* __restrict__ xr,
    float* __restrict__ h, int N) {
  __shared__ float weS[16 * 32];
  __shared__ float attS[32];
  __shared__ float bS[32];
  int t = threadIdx.x;
  for (int i = t; i < 16 * 32; i += 256) weS[i] = we[i];
  if (t < 32) { attS[t] = att[t]; bS[t] = b[t]; }
  __syncthreads();
  int lane = t & 63;
  int c = lane & 31;
  int half = lane >> 5;               // 0 or 1: which node of the pair
  int hbase = lane & 32;              // shfl base of own half
  int wid = (blockIdx.x * blockDim.x + t) >> 6;
  int nwaves = (gridDim.x * blockDim.x) >> 6;
  for (int np = wid; np * 2 < N; np += nwaves) {
    int n = np * 2 + half;
    if (n >= N) continue;             // whole half exits together
    float xr_v = xr[(size_t)n * 32 + c];
    float xl_s = xl[(size_t)n * 32 + c];
    const float4* lp4 = (const float4*)(loopA + (size_t)n * 16);
    float4 l0 = lp4[0], l1 = lp4[1], l2 = lp4[2], l3 = lp4[3];
    float ef = l0.x * weS[0 * 32 + c] + l0.y * weS[1 * 32 + c] +
               l0.z * weS[2 * 32 + c] + l0.w * weS[3 * 32 + c] +
               l1.x * weS[4 * 32 + c] + l1.y * weS[5 * 32 + c] +
               l1.z * weS[6 * 32 + c] + l1.w * weS[7 * 32 + c] +
               l2.x * weS[8 * 32 + c] + l2.y * weS[9 * 32 + c] +
               l2.z * weS[10 * 32 + c] + l2.w * weS[11 * 32 + c] +
               l3.x * weS[12 * 32 + c] + l3.y * weS[13 * 32 + c] +
               l3.z * weS[14 * 32 + c] + l3.w * weS[15 * 32 + c];
    float m = xl_s + xr_v + ef;
    m = (m > 0.f) ? m : NEG_SLOPE * m;
    float sc = m * attS[c];
#pragma unroll
    for (int off = 1; off < 32; off <<= 1) sc += __shfl_xor(sc, off);
    float ex = __expf(sc);
    float num = ex * xl_s;
    float den = ex;
    int rs = rowptr[n], re = rowptr[n + 1];
    for (int base = rs; base < re; base += 32) {
      int cnt = min(32, re - base);
      int s_l = 0, e_l = 0;
      if (c < cnt) { s_l = csr_src[base + c]; e_l = csr_eid[base + c]; }
      for (int i = 0; i < cnt; ++i) {
        int s = __shfl(s_l, hbase + i);
        int eid = __shfl(e_l, hbase + i);
        float xlv = xl[(size_t)s * 32 + c];
        const float4* e4 = (const float4*)(ea + (size_t)eid * 16);
        float4 a0 = e4[0], a1 = e4[1], a2 = e4[2], a3 = e4[3];
        float ef2 = a0.x * weS[0 * 32 + c] + a0.y * weS[1 * 32 + c] +
                    a0.z * weS[2 * 32 + c] + a0.w * weS[3 * 32 + c] +
                    a1.x * weS[4 * 32 + c] + a1.y * weS[5 * 32 + c] +
                    a1.z * weS[6 * 32 + c] + a1.w * weS[7 * 32 + c] +
                    a2.x * weS[8 * 32 + c] + a2.y * weS[9 * 32 + c] +
                    a2.z * weS[10 * 32 + c] + a2.w * weS[11 * 32 + c] +
                    a3.x * weS[12 * 32 + c] + a3.y * weS[13 * 32 + c] +
                    a3.z * weS[14 * 32 + c] + a3.w * weS[15 * 32 + c];
        float mm = xlv + xr_v + ef2;
        mm = (mm > 0.f) ? mm : NEG_SLOPE * mm;
        float s2 = mm * attS[c];
#pragma unroll
        for (int off = 1; off < 32; off <<= 1) s2 += __shfl_xor(s2, off);
        float e2 = __expf(s2);
        num += e2 * xlv;
        den += e2;
      }
    }
    h[(size_t)n * 32 + c] = fmaxf(num / fmaxf(den, 1e-16f) + bS[c], 0.f);
  }
}

// ------------------------------------------------- mean pool + fc
__global__ void pool_k(const float* __restrict__ h, const int* __restrict__ batch,
                       float* __restrict__ pooled, float* __restrict__ pcnt, int N) {
  int idx = blockIdx.x * blockDim.x + threadIdx.x;
  if (idx >= N * 32) return;
  int n = idx >> 5, c = idx & 31;
  int g = batch[n];
  atomicAdd(&pooled[(size_t)g * 32 + c], h[idx]);
  if (c == 0) atomicAdd(&pcnt[g], 1.0f);
}

__global__ void fc_k(const float* __restrict__ pooled, const float* __restrict__ pcnt,
                     const float* __restrict__ wfc, const float* __restrict__ bfc,
                     float* __restrict__ out, int G) {
  int idx = blockIdx.x * blockDim.x + threadIdx.x;
  if (idx >= G * 32) return;
  int g = idx >> 5, o = idx & 31;
  float a = 0.f;
#pragma unroll
  for (int c = 0; c < 32; ++c) a += pooled[(size_t)g * 32 + c] * wfc[c * 32 + o];
  out[idx] = a / fmaxf(pcnt[g], 1.0f) + bfc[o];
}

// ----------------------------------------------------------------- launcher
extern "C" void kernel_launch(void* const* d_in, const int* in_sizes, int n_in,
                              void* d_out, int out_size, void* d_ws, size_t ws_size,
                              hipStream_t stream) {
  const float* x   = (const float*)d_in[0];
  const int*   ei  = (const int*)d_in[1];
  const float* ea  = (const float*)d_in[2];
  const int*   bat = (const int*)d_in[3];
  const float* wl1 = (const float*)d_in[4];
  const float* wr1 = (const float*)d_in[5];
  const float* we1 = (const float*)d_in[6];
  const float* at1 = (const float*)d_in[7];
  const float* b1  = (const float*)d_in[8];
  const float* wl2 = (const float*)d_in[9];
  const float* wr2 = (const float*)d_in[10];
  const float* we2 = (const float*)d_in[11];
  const float* at2 = (const float*)d_in[12];
  const float* b2  = (const float*)d_in[13];
  const float* wfc = (const float*)d_in[14];
  const float* bfc = (const float*)d_in[15];

  const int N = in_sizes[0] / 128;
  const int E = in_sizes[1] / 2;
  const int G = 256;
  const int* srcA = ei;
  const int* dstA = ei + E;

  // ---- workspace layout (~72 MB) ----
  int* deg      = (int*)d_ws;                  // N
  int* rowptr   = deg + N;                     // N+1
  int* cursor   = rowptr + (N + 1);            // N
  int* aux      = cursor + N;                  // 512
  int* csr_src  = aux + 512;                   // E
  int* csr_eid  = csr_src + E;                 // E
  float* loopA  = (float*)(csr_eid + E);       // N*16
  float* xl1    = loopA + (size_t)N * 16;      // N*64
  float* xr1    = xl1 + (size_t)N * 64;        // N*64
  float* h1     = xr1;                         // in-place over xr1
  float* xl2    = xl1;                         // N*32 (xl1 dead after gat1)
  float* xr2    = xl1 + (size_t)N * 32;        // N*32
  float* h2     = xr2;                         // in-place over xr2
  float* pooled = (float*)cursor;              // G*32 (cursor dead after scatter)
  float* pcnt   = pooled + (size_t)G * 32;     // G

  const int naux = (N + 255) / 256;

  // ---- CSR build ----
  zero_int_k<<<(N + 255) / 256, 256, 0, stream>>>(deg, N);
  deg_count_k<<<(E + 255) / 256, 256, 0, stream>>>(dstA, deg, E);
  scan1_k<<<naux, 256, 0, stream>>>(deg, rowptr, aux, N);
  scan2_k<<<1, 512, 0, stream>>>(aux, naux);
  scan3_k<<<(N + 256) / 256, 256, 0, stream>>>(rowptr, cursor, aux, N, E);
  scatter_k<<<(E + 255) / 256, 256, 0, stream>>>(srcA, dstA, cursor, csr_src, csr_eid, E);

  // ---- self-loop attrs ----
  loop_attr_k<<<(N * 16 + 255) / 256, 256, 0, stream>>>(rowptr, csr_eid, ea, loopA, N);

  // ---- layer 1 ----
  transform1_k<<<2048, 128, 0, stream>>>(x, wl1, wr1, xl1, xr1, N);
  gat1_k<<<8192, 256, 0, stream>>>(rowptr, csr_src, csr_eid, ea, loopA, we1, at1, b1,
                                   xl1, xr1, h1, N);

  // ---- layer 2 ----
  transform2_k<<<2048, 64, 0, stream>>>(h1, wl2, wr2, xl2, xr2, N);
  hipMemsetAsync(pooled, 0, (size_t)(G * 32 + G) * sizeof(float), stream);
  gat2_k<<<8192, 256, 0, stream>>>(rowptr, csr_src, csr_eid, ea, loopA, we2, at2, b2,
                                   xl2, xr2, h2, N);

  // ---- pool + fc ----
  pool_k<<<(N * 32 + 255) / 256, 256, 0, stream>>>(h2, bat, pooled, pcnt, N);
  fc_k<<<(G * 32 + 255) / 256, 256, 0, stream>>>(pooled, pcnt, wfc, bfc, (float*)d_out, G);
}

// Round 4
// 926.237 us; speedup vs baseline: 1.7729x; 1.2948x over previous
//
#include <hip/hip_runtime.h>
#include <hip/hip_bf16.h>

#define NEG_SLOPE 0.2f

// ------------------------------------------------------------ CSR build
__global__ void zero_int_k(int* __restrict__ p, int n) {
  int i = blockIdx.x * blockDim.x + threadIdx.x;
  if (i < n) p[i] = 0;
}

__global__ void deg_count_k(const int* __restrict__ dstA, int* __restrict__ deg, int E) {
  int e = blockIdx.x * blockDim.x + threadIdx.x;
  if (e < E) atomicAdd(&deg[dstA[e]], 1);
}

// exclusive scan, 3 phases (N <= 512*256)
__global__ void scan1_k(const int* __restrict__ deg, int* __restrict__ rowptr,
                        int* __restrict__ aux, int N) {
  __shared__ int sh[256];
  int t = threadIdx.x, i = blockIdx.x * 256 + t;
  int v = (i < N) ? deg[i] : 0;
  sh[t] = v; __syncthreads();
  for (int off = 1; off < 256; off <<= 1) {
    int x = (t >= off) ? sh[t - off] : 0;
    __syncthreads();
    sh[t] += x;
    __syncthreads();
  }
  if (i < N) rowptr[i] = sh[t] - v;          // exclusive within block
  if (t == 255) aux[blockIdx.x] = sh[255];   // block total
}

__global__ void scan2_k(int* __restrict__ aux, int naux) {
  __shared__ int sh[512];
  int t = threadIdx.x;
  int v = (t < naux) ? aux[t] : 0;
  sh[t] = v; __syncthreads();
  for (int off = 1; off < 512; off <<= 1) {
    int x = (t >= off) ? sh[t - off] : 0;
    __syncthreads();
    sh[t] += x;
    __syncthreads();
  }
  if (t < naux) aux[t] = sh[t] - v;          // exclusive block offsets
}

__global__ void scan3_k(int* __restrict__ rowptr, int* __restrict__ cursor,
                        const int* __restrict__ aux, int N, int E) {
  int i = blockIdx.x * blockDim.x + threadIdx.x;
  if (i < N) {
    int r = rowptr[i] + aux[i >> 8];
    rowptr[i] = r;
    cursor[i] = r;
  } else if (i == N) {
    rowptr[N] = E;
  }
}

__global__ void scatter_k(const int* __restrict__ srcA, const int* __restrict__ dstA,
                          int* __restrict__ cursor, int* __restrict__ csr_src,
                          int* __restrict__ csr_eid, int E) {
  int e = blockIdx.x * blockDim.x + threadIdx.x;
  if (e >= E) return;
  int pos = atomicAdd(&cursor[dstA[e]], 1);
  csr_src[pos] = srcA[e];
  csr_eid[pos] = e;
}

// ------------------------------------------------------------ self-loop attr (pull)
__global__ void loop_attr_k(const int* __restrict__ rowptr, const int* __restrict__ csr_eid,
                            const float* __restrict__ ea, float* __restrict__ loopA, int N) {
  int idx = blockIdx.x * blockDim.x + threadIdx.x;
  if (idx >= N * 16) return;
  int n = idx >> 4, c = idx & 15;
  int rs = rowptr[n], re = rowptr[n + 1];
  float sum = 0.f;
  for (int i = rs; i < re; ++i) sum += ea[(size_t)csr_eid[i] * 16 + c];
  loopA[idx] = sum / fmaxf((float)(re - rs), 1.f);
}

// ------------------------------------------------- layer1 node transform (128->64 x2)
__global__ __launch_bounds__(128) void transform1_k(
    const float* __restrict__ x, const float* __restrict__ wl, const float* __restrict__ wr,
    float* __restrict__ xl, float* __restrict__ xr, int N) {
  __shared__ float wS[128 * 128];
  __shared__ float xs[4][128];
  int t = threadIdx.x;
  for (int i = t; i < 128 * 64; i += 128) {
    int k = i >> 6, j = i & 63;
    wS[k * 128 + j]      = wl[i];
    wS[k * 128 + 64 + j] = wr[i];
  }
  __syncthreads();
  for (int base = blockIdx.x * 4; base < N; base += gridDim.x * 4) {
    for (int i = t; i < 512; i += 128) {
      int node = base + (i >> 7);
      xs[i >> 7][i & 127] = (node < N) ? x[(size_t)node * 128 + (i & 127)] : 0.f;
    }
    __syncthreads();
    float a0 = 0.f, a1 = 0.f, a2 = 0.f, a3 = 0.f;
#pragma unroll
    for (int k = 0; k < 128; ++k) {
      float w = wS[k * 128 + t];
      a0 += xs[0][k] * w; a1 += xs[1][k] * w; a2 += xs[2][k] * w; a3 += xs[3][k] * w;
    }
    float* dp = (t < 64) ? xl : xr;
    int j = t & 63;
    if (base + 0 < N) dp[(size_t)(base + 0) * 64 + j] = a0;
    if (base + 1 < N) dp[(size_t)(base + 1) * 64 + j] = a1;
    if (base + 2 < N) dp[(size_t)(base + 2) * 64 + j] = a2;
    if (base + 3 < N) dp[(size_t)(base + 3) * 64 + j] = a3;
    __syncthreads();
  }
}

// ------------------------------------------------- layer2 node transform (64->32 x2)
__global__ __launch_bounds__(64) void transform2_k(
    const float* __restrict__ h, const float* __restrict__ wl, const float* __restrict__ wr,
    float* __restrict__ xl, float* __restrict__ xr, int N) {
  __shared__ float wS[64 * 64];
  __shared__ float xs[8][64];
  int t = threadIdx.x;
  for (int i = t; i < 64 * 32; i += 64) {
    int k = i >> 5, j = i & 31;
    wS[k * 64 + j]      = wl[i];
    wS[k * 64 + 32 + j] = wr[i];
  }
  __syncthreads();
  for (int base = blockIdx.x * 8; base < N; base += gridDim.x * 8) {
    for (int i = t; i < 512; i += 64) {
      int node = base + (i >> 6);
      xs[i >> 6][i & 63] = (node < N) ? h[(size_t)node * 64 + (i & 63)] : 0.f;
    }
    __syncthreads();
    float acc[8] = {0.f, 0.f, 0.f, 0.f, 0.f, 0.f, 0.f, 0.f};
#pragma unroll
    for (int k = 0; k < 64; ++k) {
      float w = wS[k * 64 + t];
#pragma unroll
      for (int i = 0; i < 8; ++i) acc[i] += xs[i][k] * w;
    }
    float* dp = (t < 32) ? xl : xr;
    int j = t & 31;
#pragma unroll
    for (int i = 0; i < 8; ++i)
      if (base + i < N) dp[(size_t)(base + i) * 32 + j] = acc[i];
    __syncthreads();
  }
}

// ------------------------------------------------- GAT layer1: one wave per node (pull)
__global__ __launch_bounds__(256) void gat1_k(
    const int* __restrict__ rowptr, const int* __restrict__ csr_src,
    const int* __restrict__ csr_eid, const float* __restrict__ ea,
    const float* __restrict__ loopA, const float* __restrict__ we,
    const float* __restrict__ att, const float* __restrict__ b,
    const float* __restrict__ xl, const float* __restrict__ xr,
    float* __restrict__ h, int N) {
  __shared__ float weS[16 * 64];
  __shared__ float attS[64];
  __shared__ float bS[64];
  int t = threadIdx.x;
  for (int i = t; i < 16 * 64; i += 256) weS[i] = we[i];
  if (t < 64) { attS[t] = att[t]; bS[t] = b[t]; }
  __syncthreads();
  int lane = t & 63;
  int wid = (blockIdx.x * blockDim.x + t) >> 6;
  int nwaves = (gridDim.x * blockDim.x) >> 6;
  for (int n = wid; n < N; n += nwaves) {
    float xr_v = xr[(size_t)n * 64 + lane];
    float xl_s = xl[(size_t)n * 64 + lane];
    // self loop
    const float4* lp4 = (const float4*)(loopA + (size_t)n * 16);
    float4 l0 = lp4[0], l1 = lp4[1], l2 = lp4[2], l3 = lp4[3];
    float ef = l0.x * weS[0 * 64 + lane] + l0.y * weS[1 * 64 + lane] +
               l0.z * weS[2 * 64 + lane] + l0.w * weS[3 * 64 + lane] +
               l1.x * weS[4 * 64 + lane] + l1.y * weS[5 * 64 + lane] +
               l1.z * weS[6 * 64 + lane] + l1.w * weS[7 * 64 + lane] +
               l2.x * weS[8 * 64 + lane] + l2.y * weS[9 * 64 + lane] +
               l2.z * weS[10 * 64 + lane] + l2.w * weS[11 * 64 + lane] +
               l3.x * weS[12 * 64 + lane] + l3.y * weS[13 * 64 + lane] +
               l3.z * weS[14 * 64 + lane] + l3.w * weS[15 * 64 + lane];
    float m = xl_s + xr_v + ef;
    m = (m > 0.f) ? m : NEG_SLOPE * m;
    float sc = m * attS[lane];
#pragma unroll
    for (int off = 1; off < 32; off <<= 1) sc += __shfl_xor(sc, off);
    float ex = __expf(sc);
    float num = ex * xl_s;
    float den = ex;
    int rs = rowptr[n], re = rowptr[n + 1];
    for (int base = rs; base < re; base += 64) {
      int cnt = min(64, re - base);
      int s_l = 0, e_l = 0;
      if (lane < cnt) { s_l = csr_src[base + lane]; e_l = csr_eid[base + lane]; }
      for (int i = 0; i < cnt; ++i) {
        int s = __shfl(s_l, i);
        int eid = __shfl(e_l, i);
        float xlv = xl[(size_t)s * 64 + lane];
        const float4* e4 = (const float4*)(ea + (size_t)eid * 16);
        float4 a0 = e4[0], a1 = e4[1], a2 = e4[2], a3 = e4[3];
        float ef2 = a0.x * weS[0 * 64 + lane] + a0.y * weS[1 * 64 + lane] +
                    a0.z * weS[2 * 64 + lane] + a0.w * weS[3 * 64 + lane] +
                    a1.x * weS[4 * 64 + lane] + a1.y * weS[5 * 64 + lane] +
                    a1.z * weS[6 * 64 + lane] + a1.w * weS[7 * 64 + lane] +
                    a2.x * weS[8 * 64 + lane] + a2.y * weS[9 * 64 + lane] +
                    a2.z * weS[10 * 64 + lane] + a2.w * weS[11 * 64 + lane] +
                    a3.x * weS[12 * 64 + lane] + a3.y * weS[13 * 64 + lane] +
                    a3.z * weS[14 * 64 + lane] + a3.w * weS[15 * 64 + lane];
        float mm = xlv + xr_v + ef2;
        mm = (mm > 0.f) ? mm : NEG_SLOPE * mm;
        float s2 = mm * attS[lane];
#pragma unroll
        for (int off = 1; off < 32; off <<= 1) s2 += __shfl_xor(s2, off);
        float e2 = __expf(s2);
        num += e2 * xlv;
        den += e2;
      }
    }
    h[(size_t)n * 64 + lane] = fmaxf(num / fmaxf(den, 1e-16f) + bS[lane], 0.f);
  }
}

// ------------------------------------------------- GAT layer2: half-wave per node
__global__ __launch_bounds__(256) void gat2_k(
    const int* __restrict__ rowptr, const int* __restrict__ csr_src,
    const int* __restrict__ csr_eid, const float* __restrict__ ea,
    const float* __restrict__ loopA, const float* __restrict__ we,
    const float* __restrict__ att, const float* __restrict__ b,
    const float* __restrict__ xl, const float* __restrict__ xr,
    float* __restrict__ h, int N) {
  __shared__ float weS[16 * 32];
  __shared__ float attS[32];
  __shared__ float bS[32];
  int t = threadIdx.x;
  for (int i = t; i < 16 * 32; i += 256) weS[i] = we[i];
  if (t < 32) { attS[t] = att[t]; bS[t] = b[t]; }
  __syncthreads();
  int lane = t & 63;
  int c = lane & 31;
  int half = lane >> 5;               // 0 or 1: which node of the pair
  int hbase = lane & 32;              // shfl base of own half
  int wid = (blockIdx.x * blockDim.x + t) >> 6;
  int nwaves = (gridDim.x * blockDim.x) >> 6;
  for (int np = wid; np * 2 < N; np += nwaves) {
    int n = np * 2 + half;
    if (n >= N) continue;             // whole half exits together
    float xr_v = xr[(size_t)n * 32 + c];
    float xl_s = xl[(size_t)n * 32 + c];
    const float4* lp4 = (const float4*)(loopA + (size_t)n * 16);
    float4 l0 = lp4[0], l1 = lp4[1], l2 = lp4[2], l3 = lp4[3];
    float ef = l0.x * weS[0 * 32 + c] + l0.y * weS[1 * 32 + c] +
               l0.z * weS[2 * 32 + c] + l0.w * weS[3 * 32 + c] +
               l1.x * weS[4 * 32 + c] + l1.y * weS[5 * 32 + c] +
               l1.z * weS[6 * 32 + c] + l1.w * weS[7 * 32 + c] +
               l2.x * weS[8 * 32 + c] + l2.y * weS[9 * 32 + c] +
               l2.z * weS[10 * 32 + c] + l2.w * weS[11 * 32 + c] +
               l3.x * weS[12 * 32 + c] + l3.y * weS[13 * 32 + c] +
               l3.z * weS[14 * 32 + c] + l3.w * weS[15 * 32 + c];
    float m = xl_s + xr_v + ef;
    m = (m > 0.f) ? m : NEG_SLOPE * m;
    float sc = m * attS[c];
#pragma unroll
    for (int off = 1; off < 32; off <<= 1) sc += __shfl_xor(sc, off);
    float ex = __expf(sc);
    float num = ex * xl_s;
    float den = ex;
    int rs = rowptr[n], re = rowptr[n + 1];
    for (int base = rs; base < re; base += 32) {
      int cnt = min(32, re - base);
      int s_l = 0, e_l = 0;
      if (c < cnt) { s_l = csr_src[base + c]; e_l = csr_eid[base + c]; }
      for (int i = 0; i < cnt; ++i) {
        int s = __shfl(s_l, hbase + i);
        int eid = __shfl(e_l, hbase + i);
        float xlv = xl[(size_t)s * 32 + c];
        const float4* e4 = (const float4*)(ea + (size_t)eid * 16);
        float4 a0 = e4[0], a1 = e4[1], a2 = e4[2], a3 = e4[3];
        float ef2 = a0.x * weS[0 * 32 + c] + a0.y * weS[1 * 32 + c] +
                    a0.z * weS[2 * 32 + c] + a0.w * weS[3 * 32 + c] +
                    a1.x * weS[4 * 32 + c] + a1.y * weS[5 * 32 + c] +
                    a1.z * weS[6 * 32 + c] + a1.w * weS[7 * 32 + c] +
                    a2.x * weS[8 * 32 + c] + a2.y * weS[9 * 32 + c] +
                    a2.z * weS[10 * 32 + c] + a2.w * weS[11 * 32 + c] +
                    a3.x * weS[12 * 32 + c] + a3.y * weS[13 * 32 + c] +
                    a3.z * weS[14 * 32 + c] + a3.w * weS[15 * 32 + c];
        float mm = xlv + xr_v + ef2;
        mm = (mm > 0.f) ? mm : NEG_SLOPE * mm;
        float s2 = mm * attS[c];
#pragma unroll
        for (int off = 1; off < 32; off <<= 1) s2 += __shfl_xor(s2, off);
        float e2 = __expf(s2);
        num += e2 * xlv;
        den += e2;
      }
    }
    h[(size_t)n * 32 + c] = fmaxf(num / fmaxf(den, 1e-16f) + bS[c], 0.f);
  }
}

// ------------------------------------------------- fused mean-pool + fc
// batch is SORTED -> graph g owns a contiguous node range; one block per graph.
__global__ __launch_bounds__(256) void pool_fc_k(
    const float* __restrict__ h, const int* __restrict__ batch,
    const float* __restrict__ wfc, const float* __restrict__ bfc,
    float* __restrict__ out, int N) {
  int g = blockIdx.x;
  __shared__ int srange[2];
  __shared__ float part[8][32];
  int t = threadIdx.x;
  if (t < 2) {
    int key = g + t;                  // t==0: lower_bound(g), t==1: lower_bound(g+1)
    int lo = 0, hi = N;
    while (lo < hi) { int mid = (lo + hi) >> 1; if (batch[mid] < key) lo = mid + 1; else hi = mid; }
    srange[t] = lo;
  }
  __syncthreads();
  int rs = srange[0], re = srange[1];
  int c = t & 31, sub = t >> 5;       // 8 sub-groups of 32 channels
  float acc = 0.f;
  for (int n = rs + sub; n < re; n += 8) acc += h[(size_t)n * 32 + c];
  part[sub][c] = acc;
  __syncthreads();
  if (sub == 0) {
    float s = part[0][c];
#pragma unroll
    for (int i = 1; i < 8; ++i) s += part[i][c];
    part[0][c] = s / fmaxf((float)(re - rs), 1.f);
  }
  __syncthreads();
  if (sub == 0) {
    float a = 0.f;
#pragma unroll
    for (int k = 0; k < 32; ++k) a += part[0][k] * wfc[k * 32 + c];
    out[g * 32 + c] = a + bfc[c];
  }
}

// ----------------------------------------------------------------- launcher
extern "C" void kernel_launch(void* const* d_in, const int* in_sizes, int n_in,
                              void* d_out, int out_size, void* d_ws, size_t ws_size,
                              hipStream_t stream) {
  const float* x   = (const float*)d_in[0];
  const int*   ei  = (const int*)d_in[1];
  const float* ea  = (const float*)d_in[2];
  const int*   bat = (const int*)d_in[3];
  const float* wl1 = (const float*)d_in[4];
  const float* wr1 = (const float*)d_in[5];
  const float* we1 = (const float*)d_in[6];
  const float* at1 = (const float*)d_in[7];
  const float* b1  = (const float*)d_in[8];
  const float* wl2 = (const float*)d_in[9];
  const float* wr2 = (const float*)d_in[10];
  const float* we2 = (const float*)d_in[11];
  const float* at2 = (const float*)d_in[12];
  const float* b2  = (const float*)d_in[13];
  const float* wfc = (const float*)d_in[14];
  const float* bfc = (const float*)d_in[15];

  const int N = in_sizes[0] / 128;
  const int E = in_sizes[1] / 2;
  const int G = 256;
  const int* srcA = ei;
  const int* dstA = ei + E;

  // ---- workspace layout (~72 MB) ----
  int* deg      = (int*)d_ws;                  // N
  int* rowptr   = deg + N;                     // N+1
  int* cursor   = rowptr + (N + 1);            // N
  int* aux      = cursor + N;                  // 512
  int* csr_src  = aux + 512;                   // E
  int* csr_eid  = csr_src + E;                 // E
  float* loopA  = (float*)(csr_eid + E);       // N*16
  float* xl1    = loopA + (size_t)N * 16;      // N*64
  float* xr1    = xl1 + (size_t)N * 64;        // N*64
  float* h1     = xr1;                         // in-place over xr1
  float* xl2    = xl1;                         // N*32 (xl1 dead after gat1)
  float* xr2    = xl1 + (size_t)N * 32;        // N*32
  float* h2     = xr2;                         // in-place over xr2

  const int naux = (N + 255) / 256;

  // ---- CSR build ----
  zero_int_k<<<(N + 255) / 256, 256, 0, stream>>>(deg, N);
  deg_count_k<<<(E + 255) / 256, 256, 0, stream>>>(dstA, deg, E);
  scan1_k<<<naux, 256, 0, stream>>>(deg, rowptr, aux, N);
  scan2_k<<<1, 512, 0, stream>>>(aux, naux);
  scan3_k<<<(N + 256) / 256, 256, 0, stream>>>(rowptr, cursor, aux, N, E);
  scatter_k<<<(E + 255) / 256, 256, 0, stream>>>(srcA, dstA, cursor, csr_src, csr_eid, E);

  // ---- self-loop attrs ----
  loop_attr_k<<<(N * 16 + 255) / 256, 256, 0, stream>>>(rowptr, csr_eid, ea, loopA, N);

  // ---- layer 1 ----
  transform1_k<<<2048, 128, 0, stream>>>(x, wl1, wr1, xl1, xr1, N);
  gat1_k<<<8192, 256, 0, stream>>>(rowptr, csr_src, csr_eid, ea, loopA, we1, at1, b1,
                                   xl1, xr1, h1, N);

  // ---- layer 2 ----
  transform2_k<<<2048, 64, 0, stream>>>(h1, wl2, wr2, xl2, xr2, N);
  gat2_k<<<8192, 256, 0, stream>>>(rowptr, csr_src, csr_eid, ea, loopA, we2, at2, b2,
                                   xl2, xr2, h2, N);

  // ---- fused pool + fc ----
  pool_fc_k<<<G, 256, 0, stream>>>(h2, bat, wfc, bfc, (float*)d_out, N);
}